// Round 1
// baseline (764.248 us; speedup 1.0000x reference)
//
#include <hip/hip_runtime.h>
#include <math.h>

#define TAU_INV (1.0f / 1000000.0f)
#define BIAS_F 1.0f

// ---------------------------------------------------------------------------
// K0: inclusive scan of per-user edge counts -> offsets[0..B]
// ---------------------------------------------------------------------------
__global__ void scan_counts(const int* __restrict__ counts,
                            int* __restrict__ offsets, int B) {
    __shared__ int sh[1024];
    int t = threadIdx.x;
    sh[t] = (t < B) ? counts[t] : 0;
    __syncthreads();
    for (int s = 1; s < 1024; s <<= 1) {
        int add = (t >= s) ? sh[t - s] : 0;
        __syncthreads();
        sh[t] += add;
        __syncthreads();
    }
    if (t < B) offsets[t + 1] = sh[t];
    if (t == 0) offsets[0] = 0;
}

// ---------------------------------------------------------------------------
// K1: edge -> (user, col-within-user) maps
// ---------------------------------------------------------------------------
__global__ void fill_edges(const int* __restrict__ offsets,
                           int* __restrict__ euser, int* __restrict__ ecol) {
    int b = blockIdx.x;
    int start = offsets[b];
    int n = offsets[b + 1] - start;
    for (int i = threadIdx.x; i < n; i += blockDim.x) {
        euser[start + i] = b;
        ecol[start + i] = i;
    }
}

// ---------------------------------------------------------------------------
// K2: Mt[j][d] = M[d][j] = sum_f W_beta[f][d] * W_friend[f][j]
//     j in [0,128) (concat input dim), d in [0,64). Stored transposed so that
//     lane d reads Mt[j*64+d] coalesced.
// ---------------------------------------------------------------------------
__global__ void compute_Mt(const float* __restrict__ Wf,   // [64,128]
                           const float* __restrict__ Wb,   // [64,64]
                           float* __restrict__ Mt) {       // [128,64]
    int idx = blockIdx.x * 256 + threadIdx.x;  // 8192 outputs
    int d = idx & 63;
    int j = idx >> 6;
    float acc = 0.f;
#pragma unroll
    for (int f = 0; f < 64; ++f)
        acc += Wb[f * 64 + d] * Wf[f * 128 + j];
    Mt[j * 64 + d] = acc;
}

// ---------------------------------------------------------------------------
// K3: SU[b][d] = sum_{j<64} Mt[j][d] * self_x[b][j]   (per-user self part)
// ---------------------------------------------------------------------------
__global__ void compute_SU(const float* __restrict__ Mt,
                           const float* __restrict__ selfx,  // [B,64]
                           float* __restrict__ SU) {         // [B,64]
    int idx = blockIdx.x * 256 + threadIdx.x;
    int d = idx & 63;
    int b = idx >> 6;
    float acc = 0.f;
#pragma unroll 8
    for (int j = 0; j < 64; ++j)
        acc += Mt[j * 64 + d] * selfx[b * 64 + j];
    SU[b * 64 + d] = acc;
}

// ---------------------------------------------------------------------------
// K4: main streaming kernel — one block per edge.
//   v[d] = SU[u][d] + sum_j Mt[64+j][d] * friend_x[e][j]
//   score[c] = common_x[e][c][:] . v      (16-lane group per c, float4 loads)
//   tf[e] = sum_c softplus(score)*exp(1 - t/TAU)*mask  ->  out[u][col]
// ---------------------------------------------------------------------------
__global__ __launch_bounds__(256) void friendship_main(
    const float* __restrict__ cx,   // [E,64,64]
    const float* __restrict__ ct,   // [E,64]
    const int*   __restrict__ mask, // [E,64]
    const float* __restrict__ fx,   // [E,64]
    const float* __restrict__ Mt,   // [128,64]
    const float* __restrict__ SU,   // [B,64]
    const int*   __restrict__ euser,
    const int*   __restrict__ ecol,
    float* __restrict__ out, int maxn) {
    int e = blockIdx.x;
    int t = threadIdx.x;
    __shared__ float vsh[64];
    __shared__ float wsum[4];

    int u = euser[e];

    // wave 0: build v into LDS (coalesced Mt reads, broadcast fx reads)
    if (t < 64) {
        float acc = SU[u * 64 + t];
        const float* f = fx + (size_t)e * 64;
        const float* m2 = Mt + 64 * 64 + t;
#pragma unroll 8
        for (int j = 0; j < 64; ++j)
            acc += m2[j * 64] * f[j];
        vsh[t] = acc;
    }
    __syncthreads();

    // each thread's 4 fixed v components (d = (t&15)*4 .. +3)
    float4 v = *(const float4*)&vsh[(t & 15) * 4];

    const float* xe = cx + (size_t)e * 4096;
    float acc = 0.f;
    int rsub = t >> 4;  // row within the 16-row chunk
#pragma unroll
    for (int iter = 0; iter < 4; ++iter) {
        float4 x = *(const float4*)&xe[iter * 1024 + t * 4];
        float p = x.x * v.x + x.y * v.y + x.z * v.z + x.w * v.w;
        // reduce the 64-element dot across the 16-lane group
        p += __shfl_xor(p, 1);
        p += __shfl_xor(p, 2);
        p += __shfl_xor(p, 4);
        p += __shfl_xor(p, 8);
        if ((t & 15) == 0) {
            int c = iter * 16 + rsub;
            float tm = ct[e * 64 + c];
            float m = (float)mask[e * 64 + c];
            // softplus(p) = max(p,0) + log1p(exp(-|p|))  (matches jax.nn.softplus)
            float sp = fmaxf(p, 0.f) + log1pf(expf(-fabsf(p)));
            acc += sp * m * expf(BIAS_F - tm * TAU_INV);
        }
    }
    // sum the 4 group-leaders per wave (lanes 0,16,32,48)
    acc += __shfl_xor(acc, 16);
    acc += __shfl_xor(acc, 32);
    if ((t & 63) == 0) wsum[t >> 6] = acc;
    __syncthreads();
    if (t == 0)
        out[(size_t)u * maxn + ecol[e]] = wsum[0] + wsum[1] + wsum[2] + wsum[3];
}

// ---------------------------------------------------------------------------
extern "C" void kernel_launch(void* const* d_in, const int* in_sizes, int n_in,
                              void* d_out, int out_size, void* d_ws,
                              size_t ws_size, hipStream_t stream) {
    const float* self_x      = (const float*)d_in[0];  // [B,64]
    const float* common_x    = (const float*)d_in[1];  // [E,64,64]
    const float* common_time = (const float*)d_in[2];  // [E,64]
    const int*   common_mask = (const int*)d_in[3];    // [E,64]
    const float* friend_x    = (const float*)d_in[4];  // [E,64]
    const int*   counts      = (const int*)d_in[5];    // [B]
    const float* W_friend    = (const float*)d_in[6];  // [64,128]
    const float* W_beta      = (const float*)d_in[7];  // [64,64]
    float* out = (float*)d_out;

    const int B = in_sizes[5];
    const int E = in_sizes[4] / 64;
    const int maxn = out_size / B;

    // workspace layout
    char* ws = (char*)d_ws;
    int*   offsets = (int*)ws;                                   // (B+1) ints
    int*   euser   = (int*)(ws + 8192);                          // E ints
    int*   ecol    = (int*)(ws + 8192 + (size_t)E * 4);          // E ints
    float* Mt      = (float*)(ws + 8192 + (size_t)E * 8);        // 128*64 f32
    float* SU      = (float*)(ws + 8192 + (size_t)E * 8 + 32768);// B*64 f32

    // output is poisoned before every timed launch — zero it (memset node is
    // graph-capturable)
    hipMemsetAsync(d_out, 0, (size_t)out_size * sizeof(float), stream);

    hipLaunchKernelGGL(scan_counts, dim3(1), dim3(1024), 0, stream,
                       counts, offsets, B);
    hipLaunchKernelGGL(fill_edges, dim3(B), dim3(64), 0, stream,
                       offsets, euser, ecol);
    hipLaunchKernelGGL(compute_Mt, dim3(32), dim3(256), 0, stream,
                       W_friend, W_beta, Mt);
    hipLaunchKernelGGL(compute_SU, dim3((B * 64) / 256), dim3(256), 0, stream,
                       Mt, self_x, SU);
    hipLaunchKernelGGL(friendship_main, dim3(E), dim3(256), 0, stream,
                       common_x, common_time, common_mask, friend_x,
                       Mt, SU, euser, ecol, out, maxn);
}

// Round 2
// 737.367 us; speedup vs baseline: 1.0365x; 1.0365x over previous
//
#include <hip/hip_runtime.h>
#include <math.h>

#define TAU_INV (1.0f / 1000000.0f)
#define BIAS_F 1.0f

// ---------------------------------------------------------------------------
// K0: inclusive scan of per-user edge counts -> offsets[0..B]
// Shuffle-based wave scan (2 barriers instead of 20).
// ---------------------------------------------------------------------------
__global__ void scan_counts(const int* __restrict__ counts,
                            int* __restrict__ offsets, int B) {
    __shared__ int wsums[16];
    int t = threadIdx.x;
    int lane = t & 63, w = t >> 6;
    int v = (t < B) ? counts[t] : 0;
    int s = v;
#pragma unroll
    for (int d = 1; d < 64; d <<= 1) {
        int n = __shfl_up(s, d);
        if (lane >= d) s += n;
    }
    if (lane == 63) wsums[w] = s;
    __syncthreads();
    if (t < 16) {
        int x = wsums[t];
#pragma unroll
        for (int d = 1; d < 16; d <<= 1) {
            int n = __shfl_up(x, d);
            if (t >= d) x += n;
        }
        wsums[t] = x;
    }
    __syncthreads();
    if (w > 0) s += wsums[w - 1];
    if (t < B) offsets[t + 1] = s;
    if (t == 0) offsets[0] = 0;
}

// ---------------------------------------------------------------------------
// K1: edge -> (user, col-within-user) maps
// ---------------------------------------------------------------------------
__global__ void fill_edges(const int* __restrict__ offsets,
                           int* __restrict__ euser, int* __restrict__ ecol) {
    int b = blockIdx.x;
    int start = offsets[b];
    int n = offsets[b + 1] - start;
    for (int i = threadIdx.x; i < n; i += blockDim.x) {
        euser[start + i] = b;
        ecol[start + i] = i;
    }
}

// ---------------------------------------------------------------------------
// K2: Mt[j][d] = sum_f W_beta[f][d] * W_friend[f][j]   ([128,64], transposed)
// ---------------------------------------------------------------------------
__global__ void compute_Mt(const float* __restrict__ Wf,   // [64,128]
                           const float* __restrict__ Wb,   // [64,64]
                           float* __restrict__ Mt) {       // [128,64]
    int idx = blockIdx.x * 256 + threadIdx.x;  // 8192 outputs
    int d = idx & 63;
    int j = idx >> 6;
    float acc = 0.f;
#pragma unroll
    for (int f = 0; f < 64; ++f)
        acc += Wb[f * 64 + d] * Wf[f * 128 + j];
    Mt[j * 64 + d] = acc;
}

// ---------------------------------------------------------------------------
// K3: SU[b][d] = sum_{j<64} Mt[j][d] * self_x[b][j]   (per-user self part)
// ---------------------------------------------------------------------------
__global__ void compute_SU(const float* __restrict__ Mt,
                           const float* __restrict__ selfx,  // [B,64]
                           float* __restrict__ SU) {         // [B,64]
    int idx = blockIdx.x * 256 + threadIdx.x;
    int d = idx & 63;
    int b = idx >> 6;
    float acc = 0.f;
#pragma unroll 8
    for (int j = 0; j < 64; ++j)
        acc += Mt[j * 64 + d] * selfx[b * 64 + j];
    SU[b * 64 + d] = acc;
}

// ---------------------------------------------------------------------------
// K4: main streaming kernel — one block per edge.
//   All 4 cx float4 loads are issued BEFORE the barrier (no LDS dependency,
//   so they stay in flight across s_barrier and overlap the v-build).
//   Wave 0 builds v[d]; wave 1 builds twt[c] = mask*exp(1 - t/TAU) in LDS.
// ---------------------------------------------------------------------------
__global__ __launch_bounds__(256) void friendship_main(
    const float* __restrict__ cx,   // [E,64,64]
    const float* __restrict__ ct,   // [E,64]
    const int*   __restrict__ mask, // [E,64]
    const float* __restrict__ fx,   // [E,64]
    const float* __restrict__ Mt,   // [128,64]
    const float* __restrict__ SU,   // [B,64]
    const int*   __restrict__ euser,
    const int*   __restrict__ ecol,
    float* __restrict__ out, int maxn) {
    int e = blockIdx.x;
    int t = threadIdx.x;
    __shared__ float vsh[64];
    __shared__ float twt[64];
    __shared__ float wsum[4];

    int u = euser[e];
    int col = ecol[e];

    // issue all global streaming loads up front — in flight across barrier
    const float* xe = cx + (size_t)e * 4096;
    float4 x0 = *(const float4*)&xe[t * 4];
    float4 x1 = *(const float4*)&xe[1024 + t * 4];
    float4 x2 = *(const float4*)&xe[2048 + t * 4];
    float4 x3 = *(const float4*)&xe[3072 + t * 4];

    if (t < 64) {
        // wave 0: v[d] = SU[u][d] + sum_j Mt2[j][d] * fx[e][j]
        float acc = SU[u * 64 + t];
        const float* f = fx + (size_t)e * 64;
        const float* m2 = Mt + 64 * 64 + t;
#pragma unroll 8
        for (int j = 0; j < 64; ++j)
            acc += m2[j * 64] * f[j];
        vsh[t] = acc;
    } else if (t < 128) {
        // wave 1: temporal*mask weight per c (coalesced 256B loads)
        int c = t - 64;
        float tm = ct[e * 64 + c];
        int m = mask[e * 64 + c];
        twt[c] = m ? expf(BIAS_F - tm * TAU_INV) : 0.f;
    }
    __syncthreads();

    // each thread's 4 fixed v components (d = (t&15)*4 .. +3)
    float4 v = *(const float4*)&vsh[(t & 15) * 4];

    float acc = 0.f;
    int rsub = t >> 4;  // row within the 16-row chunk
#pragma unroll
    for (int iter = 0; iter < 4; ++iter) {
        float4 x = (iter == 0) ? x0 : (iter == 1) ? x1 : (iter == 2) ? x2 : x3;
        float p = x.x * v.x + x.y * v.y + x.z * v.z + x.w * v.w;
        // reduce the 64-element dot across the 16-lane group
        p += __shfl_xor(p, 1);
        p += __shfl_xor(p, 2);
        p += __shfl_xor(p, 4);
        p += __shfl_xor(p, 8);
        if ((t & 15) == 0) {
            int c = iter * 16 + rsub;
            // softplus(p) = max(p,0) + log1p(exp(-|p|))
            float sp = fmaxf(p, 0.f) + log1pf(expf(-fabsf(p)));
            acc += sp * twt[c];
        }
    }
    // sum the 4 group-leaders per wave (lanes 0,16,32,48)
    acc += __shfl_xor(acc, 16);
    acc += __shfl_xor(acc, 32);
    if ((t & 63) == 0) wsum[t >> 6] = acc;
    __syncthreads();
    if (t == 0)
        out[(size_t)u * maxn + col] = wsum[0] + wsum[1] + wsum[2] + wsum[3];
}

// ---------------------------------------------------------------------------
extern "C" void kernel_launch(void* const* d_in, const int* in_sizes, int n_in,
                              void* d_out, int out_size, void* d_ws,
                              size_t ws_size, hipStream_t stream) {
    const float* self_x      = (const float*)d_in[0];  // [B,64]
    const float* common_x    = (const float*)d_in[1];  // [E,64,64]
    const float* common_time = (const float*)d_in[2];  // [E,64]
    const int*   common_mask = (const int*)d_in[3];    // [E,64]
    const float* friend_x    = (const float*)d_in[4];  // [E,64]
    const int*   counts      = (const int*)d_in[5];    // [B]
    const float* W_friend    = (const float*)d_in[6];  // [64,128]
    const float* W_beta      = (const float*)d_in[7];  // [64,64]
    float* out = (float*)d_out;

    const int B = in_sizes[5];
    const int E = in_sizes[4] / 64;
    const int maxn = out_size / B;

    // workspace layout
    char* ws = (char*)d_ws;
    int*   offsets = (int*)ws;                                   // (B+1) ints
    int*   euser   = (int*)(ws + 8192);                          // E ints
    int*   ecol    = (int*)(ws + 8192 + (size_t)E * 4);          // E ints
    float* Mt      = (float*)(ws + 8192 + (size_t)E * 8);        // 128*64 f32
    float* SU      = (float*)(ws + 8192 + (size_t)E * 8 + 32768);// B*64 f32

    // d_out is poisoned before every timed launch — zero it (memset node is
    // graph-capturable)
    hipMemsetAsync(d_out, 0, (size_t)out_size * sizeof(float), stream);

    hipLaunchKernelGGL(scan_counts, dim3(1), dim3(1024), 0, stream,
                       counts, offsets, B);
    hipLaunchKernelGGL(fill_edges, dim3(B), dim3(64), 0, stream,
                       offsets, euser, ecol);
    hipLaunchKernelGGL(compute_Mt, dim3(32), dim3(256), 0, stream,
                       W_friend, W_beta, Mt);
    hipLaunchKernelGGL(compute_SU, dim3((B * 64) / 256), dim3(256), 0, stream,
                       Mt, self_x, SU);
    hipLaunchKernelGGL(friendship_main, dim3(E), dim3(256), 0, stream,
                       common_x, common_time, common_mask, friend_x,
                       Mt, SU, euser, ecol, out, maxn);
}